// Round 5
// baseline (773.620 us; speedup 1.0000x reference)
//
#include <hip/hip_runtime.h>
#include <math.h>

#define RC2 25.0f

// Native clang vector type — required by __builtin_nontemporal_store
// (HIP's float4 is a struct and is rejected).
typedef float f32x4 __attribute__((ext_vector_type(4)));

// Kernel 1: per-atom prep — 3x3 cell inverse (uniform, redundant per thread),
// fractional coords wrapped to [0,1) into ws, and the onehot output chunk.
__global__ __launch_bounds__(256) void prep_kernel(
    const float* __restrict__ coord,
    const float* __restrict__ cell,
    const int* __restrict__ elems,
    float* __restrict__ onehot,   // d_out chunk 0: (n,4)
    float* __restrict__ frac,     // ws: (n,3)
    int n)
{
    int i = blockIdx.x * blockDim.x + threadIdx.x;
    if (i >= n) return;

    float a = cell[0], b = cell[1], c = cell[2];
    float d = cell[3], e = cell[4], f = cell[5];
    float g = cell[6], h = cell[7], k = cell[8];
    float A =  (e * k - f * h);
    float B = -(d * k - f * g);
    float C =  (d * h - e * g);
    float det = a * A + b * B + c * C;
    float inv = 1.0f / det;
    float m00 = A * inv,              m01 = -(b * k - c * h) * inv, m02 =  (b * f - c * e) * inv;
    float m10 = B * inv,              m11 =  (a * k - c * g) * inv, m12 = -(a * f - c * d) * inv;
    float m20 = C * inv,              m21 = -(a * h - b * g) * inv, m22 =  (a * e - b * d) * inv;

    float x = coord[i * 3 + 0];
    float y = coord[i * 3 + 1];
    float z = coord[i * 3 + 2];
    float fx = x * m00 + y * m10 + z * m20;
    float fy = x * m01 + y * m11 + z * m21;
    float fz = x * m02 + y * m12 + z * m22;
    fx -= floorf(fx); fy -= floorf(fy); fz -= floorf(fz);
    frac[i * 3 + 0] = fx;
    frac[i * 3 + 1] = fy;
    frac[i * 3 + 2] = fz;

    int el = elems[i];
    f32x4 oh;
    oh.x = (el == 1) ? 1.0f : 0.0f;
    oh.y = (el == 6) ? 1.0f : 0.0f;
    oh.z = (el == 7) ? 1.0f : 0.0f;
    oh.w = (el == 8) ? 1.0f : 0.0f;
    __builtin_nontemporal_store(oh, (f32x4*)(onehot + (size_t)i * 4));
}

// Kernel 2: PERSISTENT pair kernel. 2048 blocks (8/CU) grid-stride over
// work items = (row i, 1024-wide j-chunk). No LDS, no barrier (R2 showed
// LDS-coalesced writeout == direct strided stores). Each thread computes 4
// consecutive j and issues 4 nt float4 stores. Per-block fixed costs
// (create/retire, frac-load latency) amortize over ~18 iterations.
__global__ __launch_bounds__(256) void pair_kernel(
    const float* __restrict__ frac,
    const float* __restrict__ cell,
    float* __restrict__ dist,    // (n,n)
    float* __restrict__ shift,   // (n,n,3)
    int n, int nchunk, int total)
{
    const int t = threadIdx.x;

    // uniform cell (scalar loads, hoisted out of the loop)
    float c00 = cell[0], c01 = cell[1], c02 = cell[2];
    float c10 = cell[3], c11 = cell[4], c12 = cell[5];
    float c20 = cell[6], c21 = cell[7], c22 = cell[8];

    for (int chunk = blockIdx.x; chunk < total; chunk += gridDim.x) {
        int i  = chunk / nchunk;
        int c  = chunk - i * nchunk;
        int j0 = c * 1024 + t * 4;
        if (j0 >= n) continue;

        float fi0 = frac[i * 3 + 0];
        float fi1 = frac[i * 3 + 1];
        float fi2 = frac[i * 3 + 2];

        // 12 contiguous floats = frac for j0..j0+3 (j0%4==0 -> 48B-aligned)
        const float4* fj4 = (const float4*)(frac + (size_t)j0 * 3);
        float4 va = fj4[0], vb = fj4[1], vc = fj4[2];
        float fj[4][3] = {
            {va.x, va.y, va.z},
            {va.w, vb.x, vb.y},
            {vb.z, vb.w, vc.x},
            {vc.y, vc.z, vc.w}
        };

        f32x4 dout;
        f32x4 sh[3];
        float* shf = (float*)sh;

#pragma unroll
        for (int q = 0; q < 4; q++) {
            float d0 = fj[q][0] - fi0;
            float d1 = fj[q][1] - fi1;
            float d2 = fj[q][2] - fi2;
            float s0 = -rintf(d0);
            float s1 = -rintf(d1);
            float s2 = -rintf(d2);
            d0 += s0; d1 += s1; d2 += s2;
            float x = d0 * c00 + d1 * c10 + d2 * c20;
            float y = d0 * c01 + d1 * c11 + d2 * c21;
            float z = d0 * c02 + d1 * c12 + d2 * c22;
            float r2 = x * x + y * y + z * z;
            bool m = (r2 > 0.0f) && (r2 < RC2);
            dout[q] = m ? sqrtf(r2) : 0.0f;
            shf[q * 3 + 0] = s0;
            shf[q * 3 + 1] = s1;
            shf[q * 3 + 2] = s2;
        }

        // dist: wave-contiguous nontemporal float4 store
        __builtin_nontemporal_store(dout, (f32x4*)(dist + (size_t)i * n + j0));

        // shift: 3 consecutive nt float4 stores per thread (48B/lane stride)
        f32x4* sp = (f32x4*)(shift + ((size_t)i * n + j0) * 3);  // 16B aligned
        __builtin_nontemporal_store(sh[0], sp + 0);
        __builtin_nontemporal_store(sh[1], sp + 1);
        __builtin_nontemporal_store(sh[2], sp + 2);
    }
}

extern "C" void kernel_launch(void* const* d_in, const int* in_sizes, int n_in,
                              void* d_out, int out_size, void* d_ws, size_t ws_size,
                              hipStream_t stream)
{
    const float* coord = (const float*)d_in[0];   // (n,3)
    const float* cell  = (const float*)d_in[1];   // (3,3)
    const int*   elems = (const int*)d_in[2];     // (n,)
    int n = in_sizes[2];                          // 6000

    float* out    = (float*)d_out;
    float* onehot = out;                                  // n*4
    float* dist   = out + (size_t)n * 4;                  // n*n
    float* shift  = out + (size_t)n * 4 + (size_t)n * n;  // n*n*3

    float* frac = (float*)d_ws;                           // n*3 floats

    dim3 b1(256);
    dim3 g1((n + 255) / 256);
    prep_kernel<<<g1, b1, 0, stream>>>(coord, cell, elems, onehot, frac, n);

    int nchunk = (n + 1023) / 1024;   // 6 chunks of 1024 j per row
    int total  = n * nchunk;          // 36000 work items
    dim3 b2(256);
    dim3 g2(2048);                    // 8 blocks/CU, persistent grid-stride
    pair_kernel<<<g2, b2, 0, stream>>>(frac, cell, dist, shift, n, nchunk, total);
}

// Round 6
// 568.870 us; speedup vs baseline: 1.3599x; 1.3599x over previous
//
#include <hip/hip_runtime.h>
#include <math.h>

#define RC2 25.0f

// Native clang vector type — required by __builtin_nontemporal_store
// (HIP's float4 is a struct and is rejected).
typedef float f32x4 __attribute__((ext_vector_type(4)));

// Kernel 1: per-atom prep — 3x3 cell inverse (uniform, redundant per thread),
// fractional coords wrapped to [0,1) into ws, and the onehot output chunk.
__global__ __launch_bounds__(256) void prep_kernel(
    const float* __restrict__ coord,
    const float* __restrict__ cell,
    const int* __restrict__ elems,
    float* __restrict__ onehot,   // d_out chunk 0: (n,4)
    float* __restrict__ frac,     // ws: (n,3)
    int n)
{
    int i = blockIdx.x * blockDim.x + threadIdx.x;
    if (i >= n) return;

    float a = cell[0], b = cell[1], c = cell[2];
    float d = cell[3], e = cell[4], f = cell[5];
    float g = cell[6], h = cell[7], k = cell[8];
    float A =  (e * k - f * h);
    float B = -(d * k - f * g);
    float C =  (d * h - e * g);
    float det = a * A + b * B + c * C;
    float inv = 1.0f / det;
    float m00 = A * inv,              m01 = -(b * k - c * h) * inv, m02 =  (b * f - c * e) * inv;
    float m10 = B * inv,              m11 =  (a * k - c * g) * inv, m12 = -(a * f - c * d) * inv;
    float m20 = C * inv,              m21 = -(a * h - b * g) * inv, m22 =  (a * e - b * d) * inv;

    float x = coord[i * 3 + 0];
    float y = coord[i * 3 + 1];
    float z = coord[i * 3 + 2];
    float fx = x * m00 + y * m10 + z * m20;
    float fy = x * m01 + y * m11 + z * m21;
    float fz = x * m02 + y * m12 + z * m22;
    fx -= floorf(fx); fy -= floorf(fy); fz -= floorf(fz);
    frac[i * 3 + 0] = fx;
    frac[i * 3 + 1] = fy;
    frac[i * 3 + 2] = fz;

    int el = elems[i];
    f32x4 oh;
    oh.x = (el == 1) ? 1.0f : 0.0f;
    oh.y = (el == 6) ? 1.0f : 0.0f;
    oh.z = (el == 7) ? 1.0f : 0.0f;
    oh.w = (el == 8) ? 1.0f : 0.0f;
    __builtin_nontemporal_store(oh, (f32x4*)(onehot + (size_t)i * 4));
}

// Kernel 2: PERSISTENT pair kernel with R4's store path held fixed
// (LDS-coalesced shift writeout + nt full-line stores — R5 showed nt on
// strided partial lines forces HBM RMW, 1.44 TB/s). 2000 blocks x exactly 18
// iterations over work items = (row i, 1024-wide j-chunk). VALU cut ~2x:
// fast sqrt (v_sqrt_f32; absmax threshold is 0.1) and e/s/d restructure
// (s = rint(fi-fj) = -rint(fj-fi) exactly, round-half-even is odd-symmetric).
__global__ __launch_bounds__(256) void pair_kernel(
    const float* __restrict__ frac,
    const float* __restrict__ cell,
    float* __restrict__ dist,    // (n,n)
    float* __restrict__ shift,   // (n,n,3)
    int n, int nchunk, int total)
{
    __shared__ float sh_lds[1024 * 3];   // 12 KB: shift chunk in final layout

    const int t = threadIdx.x;

    // uniform cell (scalar loads, hoisted)
    float c00 = cell[0], c01 = cell[1], c02 = cell[2];
    float c10 = cell[3], c11 = cell[4], c12 = cell[5];
    float c20 = cell[6], c21 = cell[7], c22 = cell[8];

    for (int chunk = blockIdx.x; chunk < total; chunk += gridDim.x) {
        int i  = chunk / nchunk;            // uniform -> scalar pipe
        int c  = chunk - i * nchunk;
        int J0 = c * 1024;
        int j0 = J0 + t * 4;

        if (j0 < n) {
            float fi0 = frac[i * 3 + 0];    // uniform -> s_load
            float fi1 = frac[i * 3 + 1];
            float fi2 = frac[i * 3 + 2];

            // 12 contiguous floats = frac for j0..j0+3 (48B-aligned)
            const float4* fj4 = (const float4*)(frac + (size_t)j0 * 3);
            float4 va = fj4[0], vb = fj4[1], vc = fj4[2];
            float fj[4][3] = {
                {va.x, va.y, va.z},
                {va.w, vb.x, vb.y},
                {vb.z, vb.w, vc.x},
                {vc.y, vc.z, vc.w}
            };

            f32x4 dout;
            f32x4 sh[3];
            float* shf = (float*)sh;

#pragma unroll
            for (int q = 0; q < 4; q++) {
                // e = fi - fj;  s = rint(e) (== -rint(fj-fi));  d = s - e
                float e0 = fi0 - fj[q][0];
                float e1 = fi1 - fj[q][1];
                float e2 = fi2 - fj[q][2];
                float s0 = rintf(e0);
                float s1 = rintf(e1);
                float s2 = rintf(e2);
                float d0 = s0 - e0;
                float d1 = s1 - e1;
                float d2 = s2 - e2;
                float x = d0 * c00 + d1 * c10 + d2 * c20;
                float y = d0 * c01 + d1 * c11 + d2 * c21;
                float z = d0 * c02 + d1 * c12 + d2 * c22;
                float r2 = x * x + y * y + z * z;
                bool m = (r2 > 0.0f) && (r2 < RC2);
                dout[q] = m ? __builtin_amdgcn_sqrtf(r2) : 0.0f;
                shf[q * 3 + 0] = s0;
                shf[q * 3 + 1] = s1;
                shf[q * 3 + 2] = s2;
            }

            // dist: wave-contiguous nontemporal float4 store
            __builtin_nontemporal_store(dout, (f32x4*)(dist + (size_t)i * n + j0));

            // shift -> LDS in final layout
            f32x4* lp = (f32x4*)(sh_lds + t * 12);
            lp[0] = sh[0];
            lp[1] = sh[1];
            lp[2] = sh[2];
        }

        __syncthreads();

        // Coalesced nt writeout of the shift chunk: len*3 floats contiguous.
        const int len = min(1024, n - J0);      // n%4==0 -> len%4==0
        const int nf4 = (len * 3) >> 2;
        const f32x4* ls = (const f32x4*)sh_lds;
        f32x4* gp = (f32x4*)(shift + ((size_t)i * n + J0) * 3);  // 16B aligned
#pragma unroll
        for (int k = 0; k < 3; k++) {
            int q = k * 256 + t;
            if (q < nf4) __builtin_nontemporal_store(ls[q], gp + q);
        }

        __syncthreads();   // WAR: LDS reused next iteration
    }
}

extern "C" void kernel_launch(void* const* d_in, const int* in_sizes, int n_in,
                              void* d_out, int out_size, void* d_ws, size_t ws_size,
                              hipStream_t stream)
{
    const float* coord = (const float*)d_in[0];   // (n,3)
    const float* cell  = (const float*)d_in[1];   // (3,3)
    const int*   elems = (const int*)d_in[2];     // (n,)
    int n = in_sizes[2];                          // 6000

    float* out    = (float*)d_out;
    float* onehot = out;                                  // n*4
    float* dist   = out + (size_t)n * 4;                  // n*n
    float* shift  = out + (size_t)n * 4 + (size_t)n * n;  // n*n*3

    float* frac = (float*)d_ws;                           // n*3 floats

    dim3 b1(256);
    dim3 g1((n + 255) / 256);
    prep_kernel<<<g1, b1, 0, stream>>>(coord, cell, elems, onehot, frac, n);

    int nchunk = (n + 1023) / 1024;   // 6 chunks of 1024 j per row
    int total  = n * nchunk;          // 36000 work items
    dim3 b2(256);
    dim3 g2(2000);                    // 36000/2000 = exactly 18 iters/block
    pair_kernel<<<g2, b2, 0, stream>>>(frac, cell, dist, shift, n, nchunk, total);
}

// Round 7
// 560.803 us; speedup vs baseline: 1.3795x; 1.0144x over previous
//
#include <hip/hip_runtime.h>
#include <math.h>

#define RC2 25.0f

// Native clang vector type — required by __builtin_nontemporal_store
// (HIP's float4 is a struct and is rejected).
typedef float f32x4 __attribute__((ext_vector_type(4)));

// Time model (R6 post-mortem): per timed iteration the harness runs a 2.3 GB
// d_ws poison fill (~367 us) + a 576 MB d_out poison fill (~92 us) before our
// kernels. Our pair kernel runs ~96 us = 576 MB at ~6.0 TB/s, ~96% of the
// fill kernel's own demonstrated bandwidth -> store-roofline. This file is
// the best measured variant (R4): 36k blocks, LDS-coalesced shift writeout,
// nontemporal full-line stores (nt on PARTIAL lines regresses 3x - R5).

// Kernel 1: per-atom prep — 3x3 cell inverse (uniform, redundant per thread),
// fractional coords wrapped to [0,1) into ws, and the onehot output chunk.
__global__ __launch_bounds__(256) void prep_kernel(
    const float* __restrict__ coord,
    const float* __restrict__ cell,
    const int* __restrict__ elems,
    float* __restrict__ onehot,   // d_out chunk 0: (n,4)
    float* __restrict__ frac,     // ws: (n,3)
    int n)
{
    int i = blockIdx.x * blockDim.x + threadIdx.x;
    if (i >= n) return;

    float a = cell[0], b = cell[1], c = cell[2];
    float d = cell[3], e = cell[4], f = cell[5];
    float g = cell[6], h = cell[7], k = cell[8];
    float A =  (e * k - f * h);
    float B = -(d * k - f * g);
    float C =  (d * h - e * g);
    float det = a * A + b * B + c * C;
    float inv = 1.0f / det;
    float m00 = A * inv,              m01 = -(b * k - c * h) * inv, m02 =  (b * f - c * e) * inv;
    float m10 = B * inv,              m11 =  (a * k - c * g) * inv, m12 = -(a * f - c * d) * inv;
    float m20 = C * inv,              m21 = -(a * h - b * g) * inv, m22 =  (a * e - b * d) * inv;

    float x = coord[i * 3 + 0];
    float y = coord[i * 3 + 1];
    float z = coord[i * 3 + 2];
    float fx = x * m00 + y * m10 + z * m20;
    float fy = x * m01 + y * m11 + z * m21;
    float fz = x * m02 + y * m12 + z * m22;
    fx -= floorf(fx); fy -= floorf(fy); fz -= floorf(fz);
    frac[i * 3 + 0] = fx;
    frac[i * 3 + 1] = fy;
    frac[i * 3 + 2] = fz;

    int el = elems[i];
    f32x4 oh;
    oh.x = (el == 1) ? 1.0f : 0.0f;
    oh.y = (el == 6) ? 1.0f : 0.0f;
    oh.z = (el == 7) ? 1.0f : 0.0f;
    oh.w = (el == 8) ? 1.0f : 0.0f;
    __builtin_nontemporal_store(oh, (f32x4*)(onehot + (size_t)i * 4));
}

// Kernel 2: pair kernel. blockIdx.y = i (row); block covers 1024 consecutive j.
// Each thread computes 4 consecutive j. Dist stored directly (wave-contiguous
// float4, nt). Shift values staged in LDS in final layout, written out as
// lane-contiguous nontemporal float4 stores (full 128B lines -> no RMW).
__global__ __launch_bounds__(256) void pair_kernel(
    const float* __restrict__ frac,
    const float* __restrict__ cell,
    float* __restrict__ dist,    // (n,n)
    float* __restrict__ shift,   // (n,n,3)
    int n)
{
    __shared__ float sh_lds[1024 * 3];   // 12 KB: shift chunk in final layout

    const int i  = blockIdx.y;
    const int J0 = blockIdx.x * 1024;
    const int t  = threadIdx.x;
    const int j0 = J0 + t * 4;

    if (j0 < n) {
        // uniform cell (scalar loads)
        float c00 = cell[0], c01 = cell[1], c02 = cell[2];
        float c10 = cell[3], c11 = cell[4], c12 = cell[5];
        float c20 = cell[6], c21 = cell[7], c22 = cell[8];

        float fi0 = frac[i * 3 + 0];
        float fi1 = frac[i * 3 + 1];
        float fi2 = frac[i * 3 + 2];

        // 12 contiguous floats = frac for j0..j0+3 (j0%4==0 -> 48B-aligned)
        const float4* fj4 = (const float4*)(frac + (size_t)j0 * 3);
        float4 va = fj4[0], vb = fj4[1], vc = fj4[2];
        float fj[4][3] = {
            {va.x, va.y, va.z},
            {va.w, vb.x, vb.y},
            {vb.z, vb.w, vc.x},
            {vc.y, vc.z, vc.w}
        };

        f32x4 dout;
        float4 sh[3];
        float* shf = (float*)sh;

#pragma unroll
        for (int q = 0; q < 4; q++) {
            float d0 = fj[q][0] - fi0;
            float d1 = fj[q][1] - fi1;
            float d2 = fj[q][2] - fi2;
            float s0 = -rintf(d0);
            float s1 = -rintf(d1);
            float s2 = -rintf(d2);
            d0 += s0; d1 += s1; d2 += s2;
            float x = d0 * c00 + d1 * c10 + d2 * c20;
            float y = d0 * c01 + d1 * c11 + d2 * c21;
            float z = d0 * c02 + d1 * c12 + d2 * c22;
            float r2 = x * x + y * y + z * z;
            bool m = (r2 > 0.0f) && (r2 < RC2);
            dout[q] = m ? sqrtf(r2) : 0.0f;
            shf[q * 3 + 0] = s0;
            shf[q * 3 + 1] = s1;
            shf[q * 3 + 2] = s2;
        }

        // dist: wave-contiguous nontemporal float4 store
        __builtin_nontemporal_store(dout, (f32x4*)(dist + (size_t)i * n + j0));

        // shift -> LDS in final layout (3x ds_write_b128, 48B lane stride)
        float4* lp = (float4*)(sh_lds + t * 12);
        lp[0] = sh[0];
        lp[1] = sh[1];
        lp[2] = sh[2];
    }

    __syncthreads();

    // Coalesced nontemporal writeout of the shift chunk: len*3 floats.
    const int len = min(1024, n - J0);        // n % 4 == 0 -> len % 4 == 0
    const int nf4 = (len * 3) >> 2;           // float4 count
    const f32x4* ls = (const f32x4*)sh_lds;
    f32x4* gp = (f32x4*)(shift + ((size_t)i * n + J0) * 3);  // 16B aligned
#pragma unroll
    for (int k = 0; k < 3; k++) {
        int q = k * 256 + t;
        if (q < nf4) __builtin_nontemporal_store(ls[q], gp + q);
    }
}

extern "C" void kernel_launch(void* const* d_in, const int* in_sizes, int n_in,
                              void* d_out, int out_size, void* d_ws, size_t ws_size,
                              hipStream_t stream)
{
    const float* coord = (const float*)d_in[0];   // (n,3)
    const float* cell  = (const float*)d_in[1];   // (3,3)
    const int*   elems = (const int*)d_in[2];     // (n,)
    int n = in_sizes[2];                          // 6000

    float* out    = (float*)d_out;
    float* onehot = out;                                  // n*4
    float* dist   = out + (size_t)n * 4;                  // n*n
    float* shift  = out + (size_t)n * 4 + (size_t)n * n;  // n*n*3

    float* frac = (float*)d_ws;                           // n*3 floats

    dim3 b1(256);
    dim3 g1((n + 255) / 256);
    prep_kernel<<<g1, b1, 0, stream>>>(coord, cell, elems, onehot, frac, n);

    dim3 b2(256);
    dim3 g2((n + 1023) / 1024, n);
    pair_kernel<<<g2, b2, 0, stream>>>(frac, cell, dist, shift, n);
}